// Round 8
// baseline (120.586 us; speedup 1.0000x reference)
//
#include <hip/hip_runtime.h>
#include <hip/hip_bf16.h>

// out[b,co,h,w] = in[b,co,h,w] + sum_{ci,kh,kw} in[b,ci,h+kh-1,w+kw-1] * W[b,co,ci,kh,kw]
// B=16, C=128, H=W=64, K=3, pad=1, fp32 in/out.
// fp16 implicit GEMM on mfma_f32_32x32x16_f16.
// R7: sW ELIMINATED — A-operand (W fragments) read directly from global wp (L2-resident,
// XCD-swizzled reuse). LDS holds only double-buffered X tile (16.9 KB). One barrier/stage.

typedef _Float16 h8 __attribute__((ext_vector_type(8)));
typedef _Float16 h4 __attribute__((ext_vector_type(4)));
typedef float f32x16 __attribute__((ext_vector_type(16)));
typedef float f4 __attribute__((ext_vector_type(4)));

#define MFMA32 __builtin_amdgcn_mfma_f32_32x32x16_f16

// ---------------- W prepass: W[b][co][ci][kh][kw] fp32 -> wp[b][kh][kc][kwoct12][co128][ci8] fp16 ----
__global__ __launch_bounds__(256) void w_prepass(const float* __restrict__ W,
                                                 _Float16* __restrict__ wp) {
    __shared__ float raw[8 * 1153];
    const int bid = blockIdx.x;           // 256 = b16 * cog16
    const int b   = bid >> 4;
    const int co0 = (bid & 15) * 8;
    const int t   = threadIdx.x;

    const float* src = W + (size_t)(b * 128 + co0) * 1152;
#pragma unroll
    for (int i = 0; i < 9; ++i) {
        int idx  = (i * 256 + t) * 4;
        f4 v     = *(const f4*)(src + idx);
        int co_l = idx / 1152;
        int rem  = idx - co_l * 1152;
        *(f4*)&raw[co_l * 1153 + rem] = v;
    }
    __syncthreads();

#pragma unroll
    for (int i = 0; i < 9; ++i) {
        int c    = i * 256 + t;
        int jh   = c & 1;
        int co_l = (c >> 1) & 7;
        int oct  = (c >> 4) & 3;
        int r    = c >> 6;                // 0..35 = (kh*4+kc)*3 + kw
        int kw   = r % 3;
        int r2   = r / 3;
        int kc   = r2 & 3;
        int kh   = r2 >> 2;
        int cib  = kc * 32 + oct * 8 + jh * 4;
        h4 v;
#pragma unroll
        for (int jj = 0; jj < 4; ++jj)
            v[jj] = (_Float16)raw[co_l * 1153 + (cib + jj) * 9 + kh * 3 + kw];
        size_t o = ((size_t)(b * 3 + kh) * 4 + kc) * 12288 +
                   (size_t)(kw * 4 + oct) * 1024 + (size_t)(co0 + co_l) * 8 + jh * 4;
        *(h4*)&wp[o] = v;
    }
}

// ---------------- main kernel ----------------
// grid 512 = 16 b * 32 row-pairs (XCD-swizzled); 256 thr = 4 waves.
// Wave wv: co-half wvM=wv>>1, row wr=wv&1; wave tile 64co x 64px, 2x2 32x32 MFMA, acc 64 VGPR.
// A-operand: global h8 loads from wp (two coalesced 512B segments per wave inst; L1/L2-hot).
// LDS: only sX[2buf][2y][4oct][66x'][8ci] fp16 = 16.9 KB. 12 stages (kh3 x kc4), K=96/stage.

__global__ __launch_bounds__(256, 2) void conv_main(const float* __restrict__ X,
                                                    const _Float16* __restrict__ wp,
                                                    float* __restrict__ out) {
    __shared__ _Float16 sX[2 * 4224];     // 2*2*4*66*8

    const int t    = threadIdx.x;
    const int lane = t & 63;
    const int l31  = lane & 31;
    const int lhi  = lane >> 5;
    const int wv   = t >> 6;
    const int wvM  = wv >> 1;
    const int wr   = wv & 1;

    // XCD swizzle: blocks bid%8==k -> swz in [k*64,(k+1)*64) -> batches {2k,2k+1}
    const int bid   = blockIdx.x;
    const int swz   = (bid & 7) * 64 + (bid >> 3);
    const int batch = swz >> 5;
    const int h0    = (swz & 31) * 2;

    const int sy  = t >> 7;            // staging: y row 0..1
    const int xq  = (t & 15) * 4;      // 4 x-positions
    const int cio = (t >> 4) & 7;      // ci quad (ci_local = cio*4 + j)

    f32x16 acc[2][2];
#pragma unroll
    for (int mt = 0; mt < 2; ++mt)
#pragma unroll
        for (int nt = 0; nt < 2; ++nt)
#pragma unroll
            for (int r = 0; r < 16; ++r) acc[mt][nt][r] = 0.f;

    // zero halo slots (x'=0,65) in BOTH buffers, once (write_x never touches x'=0/65)
    if (t < 32) {
        int pb = t >> 4, y = (t >> 3) & 1, oct = (t >> 1) & 3, side = t & 1;
        h8 z = {};
        *(h8*)&sX[pb * 4224 + ((y * 4 + oct) * 66 + side * 65) * 8] = z;
    }

    f4 xrv[4];

    // per-thread invariant part of the W-fragment address (halfs):
    // af(mt, kwoct) at wp_slab + (kwoct*128 + wvM*64 + mt*32 + l31)*8, kwoct = kw*4+kk*2+lhi
    const int wrow = (lhi * 128 + wvM * 64 + l31) * 8;

    auto load_x = [&](int s) {
        const int kh = s >> 2, kc = s & 3;
        const int yy = h0 + sy + kh - 1;
        if (yy >= 0 && yy < 64) {
            const float* xp = X + ((size_t)(batch * 128 + kc * 32 + cio * 4) * 64 + yy) * 64 + xq;
#pragma unroll
            for (int j = 0; j < 4; ++j) xrv[j] = *(const f4*)(xp + (size_t)j * 4096);
        } else {
#pragma unroll
            for (int j = 0; j < 4; ++j) xrv[j] = (f4){0.f, 0.f, 0.f, 0.f};
        }
    };

    auto write_x = [&](int pb) {
#pragma unroll
        for (int k = 0; k < 4; ++k) {
            h4 v = {(_Float16)xrv[0][k], (_Float16)xrv[1][k],
                    (_Float16)xrv[2][k], (_Float16)xrv[3][k]};
            *(h4*)&sX[pb * 4224 + ((sy * 4 + (cio >> 1)) * 66 + xq + 1 + k) * 8 + (cio & 1) * 4] = v;
        }
    };

    auto compute = [&](int s, int pb) {
        const int kh = s >> 2, kc = s & 3;
        const _Float16* wbase = wp + ((size_t)(batch * 3 + kh) * 4 + kc) * 12288 + wrow;
        const _Float16* sXp = sX + pb * 4224;
#pragma unroll
        for (int ks = 0; ks < 6; ++ks) {
            const int kw = ks >> 1, kk = ks & 1;
            h8 af[2], bf[2];
#pragma unroll
            for (int mt = 0; mt < 2; ++mt)
                af[mt] = *(const h8*)&wbase[(size_t)((kw * 4 + kk * 2) * 128 + mt * 32) * 8];
#pragma unroll
            for (int nt = 0; nt < 2; ++nt)
                bf[nt] = *(const h8*)&sXp[((wr * 4 + kk * 2 + lhi) * 66 + nt * 32 + l31 + kw) * 8];
            __builtin_amdgcn_s_setprio(1);
#pragma unroll
            for (int mt = 0; mt < 2; ++mt)
#pragma unroll
                for (int nt = 0; nt < 2; ++nt)
                    acc[mt][nt] = MFMA32(af[mt], bf[nt], acc[mt][nt], 0, 0, 0);
            __builtin_amdgcn_s_setprio(0);
        }
    };

    // ---- prologue ----
    load_x(0);
    write_x(0);               // waits vmcnt for xrv (compiler-inserted)
    __syncthreads();          // halo zeros + stage-0 X visible

    // ---- main loop: one barrier per stage ----
    int p = 0;
#pragma unroll 1
    for (int s = 0; s < 11; ++s) {
        load_x(s + 1);           // global X loads in flight during compute(s)
        compute(s, p);
        write_x(p ^ 1);          // safe: buffer p^1 last read before previous barrier
        __syncthreads();         // stage s+1 X visible (lgkmcnt drained before s_barrier)
        p ^= 1;
    }
    compute(11, p);

    // ---- epilogue: residual add + store ----
#pragma unroll
    for (int mt = 0; mt < 2; ++mt)
#pragma unroll
        for (int nt = 0; nt < 2; ++nt)
#pragma unroll
            for (int rg = 0; rg < 16; ++rg) {
                int co = wvM * 64 + mt * 32 + (rg & 3) + 8 * (rg >> 2) + 4 * lhi;
                int x  = nt * 32 + l31;
                size_t o = ((size_t)(batch * 128 + co) * 64 + h0 + wr) * 64 + x;
                out[o] = X[o] + acc[mt][nt][rg];
            }
}

extern "C" void kernel_launch(void* const* d_in, const int* in_sizes, int n_in,
                              void* d_out, int out_size, void* d_ws, size_t ws_size,
                              hipStream_t stream) {
    const float* inp = (const float*)d_in[0];
    const float* wgt = (const float*)d_in[1];
    float* out = (float*)d_out;
    _Float16* wpk = (_Float16*)d_ws;    // 16*3*4*12288 fp16 = 4.72 MB

    w_prepass<<<256, 256, 0, stream>>>(wgt, wpk);
    conv_main<<<512, 256, 0, stream>>>(inp, wpk, out);
}

// Round 9
// 117.678 us; speedup vs baseline: 1.0247x; 1.0247x over previous
//
#include <hip/hip_runtime.h>
#include <hip/hip_bf16.h>

// out[b,co,h,w] = in[b,co,h,w] + sum_{ci,kh,kw} in[b,ci,h+kh-1,w+kw-1] * W[b,co,ci,kh,kw]
// B=16, C=128, H=W=64, K=3, pad=1, fp32 in/out.
// fp16 implicit GEMM on mfma_f32_32x32x16_f16.
// R9: occupancy 2x — 1024 blocks (1 row each), wave tile 32co x 64px (acc 32),
// LDS 8.4 KB, launch_bounds(256,4) -> 4 blocks/CU. W fragments from global (L2-hot).

typedef _Float16 h8 __attribute__((ext_vector_type(8)));
typedef _Float16 h2 __attribute__((ext_vector_type(2)));
typedef float f32x16 __attribute__((ext_vector_type(16)));
typedef float f4 __attribute__((ext_vector_type(4)));

#define MFMA32 __builtin_amdgcn_mfma_f32_32x32x16_f16

// ---------------- W prepass: W[b][co][ci][kh][kw] fp32 -> wp[b][kh][kc][kwoct12][co128][ci8] fp16 ----
__global__ __launch_bounds__(256) void w_prepass(const float* __restrict__ W,
                                                 _Float16* __restrict__ wp) {
    __shared__ float raw[8 * 1153];
    const int bid = blockIdx.x;           // 256 = b16 * cog16
    const int b   = bid >> 4;
    const int co0 = (bid & 15) * 8;
    const int t   = threadIdx.x;

    const float* src = W + (size_t)(b * 128 + co0) * 1152;
#pragma unroll
    for (int i = 0; i < 9; ++i) {
        int idx  = (i * 256 + t) * 4;
        f4 v     = *(const f4*)(src + idx);
        int co_l = idx / 1152;
        int rem  = idx - co_l * 1152;
        *(f4*)&raw[co_l * 1153 + rem] = v;
    }
    __syncthreads();

#pragma unroll
    for (int i = 0; i < 9; ++i) {
        int c    = i * 256 + t;
        int jh   = c & 1;
        int co_l = (c >> 1) & 7;
        int oct  = (c >> 4) & 3;
        int r    = c >> 6;                // 0..35 = (kh*4+kc)*3 + kw
        int kw   = r % 3;
        int r2   = r / 3;
        int kc   = r2 & 3;
        int kh   = r2 >> 2;
        int cib  = kc * 32 + oct * 8 + jh * 4;
        _Float16 v0 = (_Float16)raw[co_l * 1153 + (cib + 0) * 9 + kh * 3 + kw];
        _Float16 v1 = (_Float16)raw[co_l * 1153 + (cib + 1) * 9 + kh * 3 + kw];
        _Float16 v2 = (_Float16)raw[co_l * 1153 + (cib + 2) * 9 + kh * 3 + kw];
        _Float16 v3 = (_Float16)raw[co_l * 1153 + (cib + 3) * 9 + kh * 3 + kw];
        size_t o = ((size_t)(b * 3 + kh) * 4 + kc) * 12288 +
                   (size_t)(kw * 4 + oct) * 1024 + (size_t)(co0 + co_l) * 8 + jh * 4;
        wp[o + 0] = v0; wp[o + 1] = v1; wp[o + 2] = v2; wp[o + 3] = v3;
    }
}

// ---------------- main kernel ----------------
// grid 1024 = 16 b * 64 rows (XCD-swizzled); 256 thr = 4 waves.
// Wave wv: co tile [wv*32, wv*32+32), px 0..63 -> 1x2 32x32 MFMA tiles, acc 32 regs.
// A-operand: global h8 loads from wp (coalesced 512B segments; L1/L2-hot).
// LDS: sX[2buf][4oct][66x'][8ci] fp16 = 8448 B. 12 stages (kh3 x kc4), K=96/stage.

__global__ __launch_bounds__(256, 4) void conv_main(const float* __restrict__ X,
                                                    const _Float16* __restrict__ wp,
                                                    float* __restrict__ out) {
    __shared__ _Float16 sX[2 * 2112];     // 2 * 4*66*8

    const int t    = threadIdx.x;
    const int lane = t & 63;
    const int l31  = lane & 31;
    const int lhi  = lane >> 5;
    const int wv   = t >> 6;

    // XCD swizzle: 1024 % 8 == 0 -> bijective
    const int bid   = blockIdx.x;
    const int swz   = (bid & 7) * 128 + (bid >> 3);
    const int batch = swz >> 6;
    const int h     = swz & 63;

    // staging map: thread -> ci pair (2p, 2p+1), 4 x-positions
    const int p  = t >> 4;             // 0..15
    const int xq = (t & 15) * 4;

    f32x16 acc[2];
#pragma unroll
    for (int nt = 0; nt < 2; ++nt)
#pragma unroll
        for (int r = 0; r < 16; ++r) acc[nt][r] = 0.f;

    // zero halo slots (x'=0,65) in BOTH buffers, once (write_x only touches x' in [1,64])
    if (t < 16) {
        int pb = t >> 3, oct = (t >> 1) & 3, side = t & 1;
        h8 z = {};
        *(h8*)&sX[pb * 2112 + (oct * 66 + side * 65) * 8] = z;
    }

    f4 xa, xb;    // X stage regs: ci 2p (xa), 2p+1 (xb), 4 x each

    // per-thread invariant part of W-fragment address:
    // af(kw,kk) at slab + ((kw*4+kk*2+lhi)*128 + wv*32 + l31)*8
    const int wrow = (lhi * 128 + wv * 32 + l31) * 8;

    auto load_x = [&](int s) {
        const int kh = s >> 2, kc = s & 3;
        const int yy = h + kh - 1;
        if (yy >= 0 && yy < 64) {
            const float* xp = X + ((size_t)(batch * 128 + kc * 32 + 2 * p) * 64 + yy) * 64 + xq;
            xa = *(const f4*)xp;
            xb = *(const f4*)(xp + 4096);
        } else {
            xa = (f4){0.f, 0.f, 0.f, 0.f};
            xb = (f4){0.f, 0.f, 0.f, 0.f};
        }
    };

    auto write_x = [&](int pb) {
        const int oct = p >> 2;
        const int sub = (p & 3) * 2;
#pragma unroll
        for (int k = 0; k < 4; ++k) {
            h2 v = {(_Float16)xa[k], (_Float16)xb[k]};
            *(h2*)&sX[pb * 2112 + (oct * 66 + xq + 1 + k) * 8 + sub] = v;
        }
    };

    auto compute = [&](int s, int pb) {
        const int kh = s >> 2, kc = s & 3;
        const _Float16* wbase = wp + ((size_t)(batch * 3 + kh) * 4 + kc) * 12288 + wrow;
        const _Float16* sXp = sX + pb * 2112;
#pragma unroll
        for (int ks = 0; ks < 6; ++ks) {
            const int kw = ks >> 1, kk = ks & 1;
            h8 af, bf[2];
            af = *(const h8*)&wbase[(size_t)((kw * 4 + kk * 2) * 128) * 8];
#pragma unroll
            for (int nt = 0; nt < 2; ++nt)
                bf[nt] = *(const h8*)&sXp[((kk * 2 + lhi) * 66 + nt * 32 + l31 + kw) * 8];
            __builtin_amdgcn_s_setprio(1);
#pragma unroll
            for (int nt = 0; nt < 2; ++nt)
                acc[nt] = MFMA32(af, bf[nt], acc[nt], 0, 0, 0);
            __builtin_amdgcn_s_setprio(0);
        }
    };

    // ---- prologue ----
    load_x(0);
    write_x(0);               // compiler-inserted vmcnt wait on xa/xb
    __syncthreads();          // halo zeros + stage-0 X visible

    // ---- main loop: one barrier per stage ----
    int pbuf = 0;
#pragma unroll 1
    for (int s = 0; s < 11; ++s) {
        load_x(s + 1);           // global X loads in flight during compute(s)
        compute(s, pbuf);
        write_x(pbuf ^ 1);       // safe: buffer pbuf^1 last read before previous barrier
        __syncthreads();         // stage s+1 X visible
        pbuf ^= 1;
    }
    compute(11, pbuf);

    // ---- epilogue: residual add + store ----
#pragma unroll
    for (int nt = 0; nt < 2; ++nt)
#pragma unroll
        for (int rg = 0; rg < 16; ++rg) {
            int co = wv * 32 + (rg & 3) + 8 * (rg >> 2) + 4 * lhi;
            int x  = nt * 32 + l31;
            size_t o = ((size_t)(batch * 128 + co) * 64 + h) * 64 + x;
            out[o] = X[o] + acc[nt][rg];
        }
}

extern "C" void kernel_launch(void* const* d_in, const int* in_sizes, int n_in,
                              void* d_out, int out_size, void* d_ws, size_t ws_size,
                              hipStream_t stream) {
    const float* inp = (const float*)d_in[0];
    const float* wgt = (const float*)d_in[1];
    float* out = (float*)d_out;
    _Float16* wpk = (_Float16*)d_ws;    // 16*3*4*12288 fp16 = 4.72 MB

    w_prepass<<<256, 256, 0, stream>>>(wgt, wpk);
    conv_main<<<1024, 256, 0, stream>>>(inp, wpk, out);
}